// Round 4
// baseline (942.132 us; speedup 1.0000x reference)
//
#include <hip/hip_runtime.h>

typedef __attribute__((ext_vector_type(8))) short short8;
typedef __attribute__((ext_vector_type(16))) float f32x16;

// ws layout:
//   Ft2  [z=512][yy=66][xx=66][8] bf16 halo-padded features, z = c*8 + b   (35.68 MB)
//   wt2  [i=576][n=128][8] bf16 B, i-major (c-contiguous: i = c*9 + j)     (1.18 MB)
#define FT2_SHORTS (512u * 4356u * 8u)
#define PLANE16    4356

typedef __attribute__((address_space(3))) unsigned int lds_u32_t;
typedef __attribute__((address_space(1))) const unsigned int g_u32_t;

__device__ __forceinline__ unsigned short f2bf(float x) {
    union { float f; unsigned u; } v; v.f = x;
    unsigned r = v.u + 0x7FFFu + ((v.u >> 16) & 1u);   // RNE bf16
    return (unsigned short)(r >> 16);
}

__device__ __forceinline__ void feat8(float p, unsigned short* uf) {
    float e   = __expf(-p);
    float sig = 1.f / (1.f + e);
    uf[0] = f2bf(p * sig);
    float u  = p * 1.5f + 4.5f;
    float fj = floorf(u);
    int   j0 = (int)fj;
    float t  = u - fj;
    bool  inr = (u >= 0.f) && (u < 9.f);
    float t2 = t * t, t3 = t2 * t;
    const float c16 = 1.f / 6.f;
    float r0 = t3 * c16;
    float r1 = (-3.f * t3 + 3.f * t2 + 3.f * t + 1.f) * c16;
    float r2 = (3.f * t3 - 6.f * t2 + 4.f) * c16;
    float s1 = 1.f - t;
    float r3 = s1 * s1 * s1 * c16;
#pragma unroll
    for (int g = 0; g < 6; ++g) {
        int r = j0 - g;
        float v = (r == 0) ? r0 : ((r == 1) ? r1 : ((r == 2) ? r2 : ((r == 3) ? r3 : 0.f)));
        uf[1 + g] = f2bf(inr ? v : 0.f);
    }
    uf[7] = 0;
}

// ---- Fused prep: per block (512): 144 B-chunks + 1 halo plane + 1 feature line ----
__global__ __launch_bounds__(256)
void prep_all(const float* __restrict__ x,
              const float* __restrict__ bw, const float* __restrict__ sw,
              unsigned short* __restrict__ ft, unsigned short* __restrict__ wt) {
    const int blk = blockIdx.x;          // 0..511
    const int tid = threadIdx.x;

    // (1) B prep into i-major layout: wt[i][n][8]
    if (tid < 144) {
        int idx = blk * 144 + tid;
        int o = idx / 576;
        int i = idx - o * 576;
        union { unsigned short u[8]; uint4 v; } pk;
        pk.u[0] = f2bf(bw[o * 576 + i]);
        const float* s = sw + (size_t)(o * 576 + i) * 6;
#pragma unroll
        for (int f = 0; f < 6; ++f) pk.u[1 + f] = f2bf(s[f]);
        pk.u[7] = 0;
        *(uint4*)(wt + ((size_t)i * 1024 + o * 8)) = pk.v;
    }

    // (2) halo plane z = blk: feat8(0) into the 260 border cells
    {
        short8 pad = { 0, 0, (short)0x3CAB, (short)0x3EF5,
                       (short)0x3EF5, (short)0x3CAB, 0, 0 };
        for (int t = tid; t < 260; t += 256) {
            int yy, xx;
            if (t < 66)       { yy = 0;       xx = t; }
            else if (t < 132) { yy = 65;      xx = t - 66; }
            else if (t < 196) { yy = t - 131; xx = 0; }
            else              { yy = t - 195; xx = 65; }
            ((short8*)ft)[blk * PLANE16 + yy * 66 + xx] = pad;
        }
    }

    // (3) features for line = blk (b = blk>>6, y = blk&63)
    __shared__ float Xl[64 * 65];
    const int b = blk >> 6, y = blk & 63;
    const float* xl = x + (size_t)blk * 4096;
    for (int f4 = tid; f4 < 1024; f4 += 256) {
        float4 v = ((const float4*)xl)[f4];
        int xx = f4 >> 4, c4 = (f4 & 15) << 2;
        float* d = &Xl[xx * 65 + c4];
        d[0] = v.x; d[1] = v.y; d[2] = v.z; d[3] = v.w;
    }
    __syncthreads();
    const int xx = tid & 63;
    const int cw = tid >> 6;
#pragma unroll 4
    for (int p = 0; p < 16; ++p) {
        int c = cw + (p << 2);
        float pv = Xl[xx * 65 + c];
        union { unsigned short u[8]; uint4 v; } pk;
        feat8(pv, pk.u);
        size_t o16 = (size_t)(c * 8 + b) * PLANE16 + (y + 1) * 66 + (xx + 1);
        *(uint4*)(ft + (o16 << 3)) = pk.v;
    }
}

// ---- Main GEMM: tile 128m x 128n, FULL K, grid 256, block 1024 (16 waves) ----
// K-loop restructured by c-PAIRS (32 phases, K=144 = 9 K16 steps each):
//   - A: per c-plane, 4 halo rows staged ONCE (6 KB region incl slack); the
//     (kh,kw) 3x3 redundancy is resolved at ds_read time via address offsets.
//     Cuts A DMA bytes ~4.5x (the measured wall is ~20 B/cy/CU of staged bytes).
//   - B: i-major wt -> each c-pair's 18 chunks = one contiguous 36 KB stage.
// LDS buffer 48 KB: [B: 18 chunks x 128n x 16B = 36864B][A: 2 planes x 6144B].
// TRIPLE-buffered = 144 KB. 48 loads/phase = 3 per wave (uniform vmcnt).
// Waves (kq,mh,nh): kq splits the 9 K16 steps {0,1|2,3|4,5|6,7,8}; (mh,nh)
// picks the 64x64 output quadrant. Epilogue: 3-round LDS K-reduction + store.
#define BUF_SHORTS 24576

#define STAGE(c2_, q_)                                                                \
    {                                                                                 \
        unsigned short* bufq = Bufs + (q_) * BUF_SHORTS;                              \
        _Pragma("unroll")                                                             \
        for (int t = 0; t < 3; ++t) {                                                 \
            int u = wave * 3 + t;            /* 0..47: u<36 = B, u>=36 = A */         \
            if (u < 36) {                                                             \
                const unsigned short* src =                                           \
                    wt + (size_t)(c2_) * 18432 + u * 512 + lane * 8;                  \
                unsigned short* dst = bufq + u * 512 + lane * 8;                      \
                __builtin_amdgcn_global_load_lds((g_u32_t*)src, (lds_u32_t*)dst,      \
                                                 16, 0, 0);                           \
            } else {                                                                  \
                int ua = u - 36;             /* 0..11 */                              \
                int cp = ua >= 6;                                                     \
                int q6 = ua - cp * 6;        /* 0..5 */                               \
                int z  = (((c2_) << 1) + cp) * 8 + b;                                 \
                const unsigned short* src = ft +                                      \
                    ((size_t)z * PLANE16 + y0 * 66) * 8 + q6 * 512 + lane * 8;        \
                unsigned short* dst = bufq + 18432 + cp * 3072 + q6 * 512 + lane * 8; \
                __builtin_amdgcn_global_load_lds((g_u32_t*)src, (lds_u32_t*)dst,      \
                                                 16, 0, 0);                           \
            }                                                                         \
        }                                                                             \
    }

// One K16 step s (0..8): lane k-half h picks chunk t0 = 2s+h; decode (cp,kh,kw).
#define DOSTEP(s_)                                                                    \
    {                                                                                 \
        int t0 = 2 * (s_) + h;                                                        \
        int cp = (t0 >= 9);                                                           \
        int j  = t0 - 9 * cp;                                                         \
        int kh = (j * 11) >> 5;                                                       \
        int kw = j - kh * 3;                                                          \
        const unsigned short* Ab = bufr + 18432 + cp * 3072                           \
                                   + ((mh + kh) * 66 + kw) * 8;                       \
        const unsigned short* Bb = bufr + t0 * 1024 + nh * 512;                       \
        short8 a0 = *(const short8*)(Ab + l32 * 8);                                   \
        short8 a1 = *(const short8*)(Ab + (32 + l32) * 8);                            \
        short8 b0 = *(const short8*)(Bb + l32 * 8);                                   \
        short8 b1 = *(const short8*)(Bb + (256 + l32 * 8));                           \
        acc00 = __builtin_amdgcn_mfma_f32_32x32x16_bf16(a0, b0, acc00, 0, 0, 0);      \
        acc01 = __builtin_amdgcn_mfma_f32_32x32x16_bf16(a0, b1, acc01, 0, 0, 0);      \
        acc10 = __builtin_amdgcn_mfma_f32_32x32x16_bf16(a1, b0, acc10, 0, 0, 0);      \
        acc11 = __builtin_amdgcn_mfma_f32_32x32x16_bf16(a1, b1, acc11, 0, 0, 0);      \
    }

#define COMPUTE(q_)                                                                   \
    {                                                                                 \
        const unsigned short* bufr = Bufs + (q_) * BUF_SHORTS;                        \
        if (kq == 0)      { DOSTEP(0) DOSTEP(1) }                                     \
        else if (kq == 1) { DOSTEP(2) DOSTEP(3) }                                     \
        else if (kq == 2) { DOSTEP(4) DOSTEP(5) }                                     \
        else              { DOSTEP(6) DOSTEP(7) DOSTEP(8) }                           \
    }

#define PHASE(q_, n_, stagec2, dostage_)                                              \
    {                                                                                 \
        asm volatile("s_waitcnt vmcnt(" #n_ ")" ::: "memory");                        \
        __builtin_amdgcn_s_barrier();                                                 \
        asm volatile("" ::: "memory");                                                \
        __builtin_amdgcn_s_setprio(1);                                                \
        COMPUTE(q_)                                                                   \
        __builtin_amdgcn_s_setprio(0);                                                \
        asm volatile("" ::: "memory");                                                \
        __builtin_amdgcn_s_barrier();                                                 \
        asm volatile("" ::: "memory");                                                \
        if (dostage_) STAGE(stagec2, q_);                                             \
    }

// Epilogue reduce helpers: conflict-free float4 layout (lane-stride 16 B).
#define DUMPA(base_, A_)                                                              \
    {   float4* s4 = (float4*)(red + (base_));                                        \
        _Pragma("unroll")                                                             \
        for (int c = 0; c < 4; ++c)                                                   \
            s4[c * 64 + lane] = make_float4(A_[4*c], A_[4*c+1], A_[4*c+2], A_[4*c+3]); }
#define ADDA(base_, A_)                                                               \
    {   const float4* s4 = (const float4*)(red + (base_));                            \
        _Pragma("unroll")                                                             \
        for (int c = 0; c < 4; ++c) {                                                 \
            float4 rv = s4[c * 64 + lane];                                            \
            A_[4*c] += rv.x; A_[4*c+1] += rv.y; A_[4*c+2] += rv.z; A_[4*c+3] += rv.w; } }

__global__ __launch_bounds__(1024, 4)
void convkan_gemm(const unsigned short* __restrict__ ft,
                  const unsigned short* __restrict__ wt,
                  const float* __restrict__ bias,
                  float* __restrict__ out) {
    extern __shared__ unsigned short Bufs[];     // 3 x 24576 shorts = 144 KB

    const int tid  = threadIdx.x;
    const int mb   = blockIdx.x;                 // 0..255, 128 px (2 lines) each
    const int lane = tid & 63;
    const int wave = tid >> 6;                   // 0..15
    const int kq   = wave >> 2;                  // K-quarter (steps) 0..3
    const int mh   = (wave >> 1) & 1;            // m-half = output line within pair
    const int nh   = wave & 1;                   // n-half (64 ch)
    const int l32  = lane & 31;
    const int h    = lane >> 5;                  // k-half within MFMA K16

    const int b  = mb >> 5;                      // image 0..7
    const int y0 = (mb & 31) << 1;               // first of 2 lines

    f32x16 acc00, acc01, acc10, acc11;
#pragma unroll
    for (int e = 0; e < 16; ++e) { acc00[e] = 0.f; acc01[e] = 0.f; acc10[e] = 0.f; acc11[e] = 0.f; }

    // prologue: fill the 3-deep pipeline (c-pairs 0,1,2)
    STAGE(0, 0);
    STAGE(1, 1);
    STAGE(2, 2);

    // steady state: phases 0..26 stage c-pairs 3..29
    for (int it3 = 0; it3 < 9; ++it3) {
        const int it = it3 * 3;
        PHASE(0, 6, it + 3, true)
        PHASE(1, 6, it + 4, true)
        PHASE(2, 6, it + 5, true)
    }
    // phases 27..31: stage 30, 31, then drain
    PHASE(0, 6, 30, true)
    PHASE(1, 6, 31, true)
    PHASE(2, 6, 0, false)
    PHASE(0, 3, 0, false)
    PHASE(1, 0, 0, false)

    // ---- K-partial reduction across kq (3 rounds via LDS), then store ----
    __syncthreads();
    float* red = (float*)Bufs;
    const int grp = mh * 2 + nh;                 // 0..3

    if (kq >= 2) { DUMPA(((grp << 1) + (kq - 2)) * 2048,        acc00);
                   DUMPA(((grp << 1) + (kq - 2)) * 2048 + 1024, acc01); }
    __syncthreads();
    if (kq < 2)  { ADDA(((grp << 1) + kq) * 2048,        acc00);
                   ADDA(((grp << 1) + kq) * 2048 + 1024, acc01); }
    __syncthreads();
    if (kq >= 2) { DUMPA(((grp << 1) + (kq - 2)) * 2048,        acc10);
                   DUMPA(((grp << 1) + (kq - 2)) * 2048 + 1024, acc11); }
    __syncthreads();
    if (kq < 2)  { ADDA(((grp << 1) + kq) * 2048,        acc10);
                   ADDA(((grp << 1) + kq) * 2048 + 1024, acc11); }
    __syncthreads();
    if (kq == 1) { DUMPA(grp * 4096,        acc00); DUMPA(grp * 4096 + 1024, acc01);
                   DUMPA(grp * 4096 + 2048, acc10); DUMPA(grp * 4096 + 3072, acc11); }
    __syncthreads();
    if (kq == 0) {
        ADDA(grp * 4096,        acc00); ADDA(grp * 4096 + 1024, acc01);
        ADDA(grp * 4096 + 2048, acc10); ADDA(grp * 4096 + 3072, acc11);

        const int ncol = nh * 64 + l32;
        const float bv0 = bias[ncol];
        const float bv1 = bias[ncol + 32];
        const int prow = mb * 128 + mh * 64;
#pragma unroll
        for (int r = 0; r < 16; ++r) {
            int mrow = (r & 3) + ((r >> 2) << 3) + 4 * h;
            float* p = out + (size_t)(prow + mrow) * 128 + ncol;
            p[0]  = acc00[r] + bv0;
            p[32] = acc01[r] + bv1;
            float* p2 = out + (size_t)(prow + 32 + mrow) * 128 + ncol;
            p2[0]  = acc10[r] + bv0;
            p2[32] = acc11[r] + bv1;
        }
    }
}

extern "C" void kernel_launch(void* const* d_in, const int* in_sizes, int n_in,
                              void* d_out, int out_size, void* d_ws, size_t ws_size,
                              hipStream_t stream) {
    (void)in_sizes; (void)n_in; (void)ws_size; (void)out_size;
    const float* x        = (const float*)d_in[0];
    const float* base_w   = (const float*)d_in[1];
    const float* spline_w = (const float*)d_in[2];
    const float* bias     = (const float*)d_in[3];
    float* out = (float*)d_out;

    unsigned short* ft = (unsigned short*)d_ws;      // 35.68 MB halo features
    unsigned short* wt = ft + FT2_SHORTS;            // 1.18 MB tiled B (i-major)

    hipLaunchKernelGGL(prep_all, dim3(512), dim3(256), 0, stream,
                       x, base_w, spline_w, ft, wt);

    const int shmem = 3 * BUF_SHORTS * 2;            // 144 KB
    (void)hipFuncSetAttribute((const void*)convkan_gemm,
                              hipFuncAttributeMaxDynamicSharedMemorySize, shmem);
    hipLaunchKernelGGL(convkan_gemm, dim3(256), dim3(1024), shmem, stream,
                       ft, wt, bias, out);
}

// Round 5
// 177.104 us; speedup vs baseline: 5.3197x; 5.3197x over previous
//
#include <hip/hip_runtime.h>

typedef __attribute__((ext_vector_type(8))) short short8;
typedef __attribute__((ext_vector_type(16))) float f32x16;

// ws layout:
//   Ft2  [z=512][yy=66][xx=66][8] bf16 halo-padded features, z = c*8 + b   (35.68 MB)
//   wt2  [i=576][n=128][8] bf16 B, i-major (c-contiguous: i = c*9 + j)     (1.18 MB)
#define FT2_SHORTS (512u * 4356u * 8u)
#define PLANE16    4356

typedef __attribute__((address_space(3))) unsigned int lds_u32_t;
typedef __attribute__((address_space(1))) const unsigned int g_u32_t;

__device__ __forceinline__ unsigned short f2bf(float x) {
    union { float f; unsigned u; } v; v.f = x;
    unsigned r = v.u + 0x7FFFu + ((v.u >> 16) & 1u);   // RNE bf16
    return (unsigned short)(r >> 16);
}

__device__ __forceinline__ void feat8(float p, unsigned short* uf) {
    float e   = __expf(-p);
    float sig = 1.f / (1.f + e);
    uf[0] = f2bf(p * sig);
    float u  = p * 1.5f + 4.5f;
    float fj = floorf(u);
    int   j0 = (int)fj;
    float t  = u - fj;
    bool  inr = (u >= 0.f) && (u < 9.f);
    float t2 = t * t, t3 = t2 * t;
    const float c16 = 1.f / 6.f;
    float r0 = t3 * c16;
    float r1 = (-3.f * t3 + 3.f * t2 + 3.f * t + 1.f) * c16;
    float r2 = (3.f * t3 - 6.f * t2 + 4.f) * c16;
    float s1 = 1.f - t;
    float r3 = s1 * s1 * s1 * c16;
#pragma unroll
    for (int g = 0; g < 6; ++g) {
        int r = j0 - g;
        float v = (r == 0) ? r0 : ((r == 1) ? r1 : ((r == 2) ? r2 : ((r == 3) ? r3 : 0.f)));
        uf[1 + g] = f2bf(inr ? v : 0.f);
    }
    uf[7] = 0;
}

// ---- Fused prep: per block (512): 144 B-chunks + 1 halo plane + 1 feature line ----
__global__ __launch_bounds__(256)
void prep_all(const float* __restrict__ x,
              const float* __restrict__ bw, const float* __restrict__ sw,
              unsigned short* __restrict__ ft, unsigned short* __restrict__ wt) {
    const int blk = blockIdx.x;          // 0..511
    const int tid = threadIdx.x;

    // (1) B prep into i-major layout: wt[i][n][8]
    if (tid < 144) {
        int idx = blk * 144 + tid;
        int o = idx / 576;
        int i = idx - o * 576;
        union { unsigned short u[8]; uint4 v; } pk;
        pk.u[0] = f2bf(bw[o * 576 + i]);
        const float* s = sw + (size_t)(o * 576 + i) * 6;
#pragma unroll
        for (int f = 0; f < 6; ++f) pk.u[1 + f] = f2bf(s[f]);
        pk.u[7] = 0;
        *(uint4*)(wt + ((size_t)i * 1024 + o * 8)) = pk.v;
    }

    // (2) halo plane z = blk: feat8(0) into the 260 border cells
    {
        short8 pad = { 0, 0, (short)0x3CAB, (short)0x3EF5,
                       (short)0x3EF5, (short)0x3CAB, 0, 0 };
        for (int t = tid; t < 260; t += 256) {
            int yy, xx;
            if (t < 66)       { yy = 0;       xx = t; }
            else if (t < 132) { yy = 65;      xx = t - 66; }
            else if (t < 196) { yy = t - 131; xx = 0; }
            else              { yy = t - 195; xx = 65; }
            ((short8*)ft)[blk * PLANE16 + yy * 66 + xx] = pad;
        }
    }

    // (3) features for line = blk (b = blk>>6, y = blk&63)
    __shared__ float Xl[64 * 65];
    const int b = blk >> 6, y = blk & 63;
    const float* xl = x + (size_t)blk * 4096;
    for (int f4 = tid; f4 < 1024; f4 += 256) {
        float4 v = ((const float4*)xl)[f4];
        int xx = f4 >> 4, c4 = (f4 & 15) << 2;
        float* d = &Xl[xx * 65 + c4];
        d[0] = v.x; d[1] = v.y; d[2] = v.z; d[3] = v.w;
    }
    __syncthreads();
    const int xx = tid & 63;
    const int cw = tid >> 6;
#pragma unroll 4
    for (int p = 0; p < 16; ++p) {
        int c = cw + (p << 2);
        float pv = Xl[xx * 65 + c];
        union { unsigned short u[8]; uint4 v; } pk;
        feat8(pv, pk.u);
        size_t o16 = (size_t)(c * 8 + b) * PLANE16 + (y + 1) * 66 + (xx + 1);
        *(uint4*)(ft + (o16 << 3)) = pk.v;
    }
}

// ---- Main GEMM: tile 128m x 128n, FULL K, grid 256, block 768 (12 waves) ----
// K-loop by c-PAIRS: 32 phases, each K=144 (2 c-planes x 9 j x 8 e = 9 K16 steps).
//   - A: per c-plane, the 4 halo rows staged ONCE (6 KB region); the (kh,kw)
//     3x3 redundancy resolved at ds_read time via precomputed address offsets.
//   - B: i-major wt -> each c-pair's 18 chunks = one contiguous 36 KB stage.
// Staged bytes/block = 32 x 48 KB = 1.54 MB (-33% vs slab scheme).
// Waves (sq 0..2, mh, nh): sq splits the 9 steps UNIFORMLY 3/3/3 -> every wave
// runs the identical straight-line body (12 ds_read + 12 MFMA per phase); all
// LDS offsets precomputed into named scalars (no control flow in hot loop —
// R4's branchy compute caused accumulator spills: 1.84 GB scratch writes).
// LDS buffer 48 KB: [B: 18 x 128n x 16B = 36864 B][A: 2 planes x 6144 B].
// Triple-buffered = 144 KB; 48 loads/phase = 4/wave -> steady vmcnt(8).
// Epilogue: one-round 3-way LDS K-reduction, then coalesced stores.
#define BUF_SHORTS 24576

#define STAGE(c2_, q_)                                                                \
    {                                                                                 \
        unsigned short* bufq = Bufs + (q_) * BUF_SHORTS;                              \
        _Pragma("unroll")                                                             \
        for (int t = 0; t < 4; ++t) {                                                 \
            int u = wave * 4 + t;            /* 0..47: u<36 = B, u>=36 = A */         \
            if (u < 36) {                                                             \
                const unsigned short* src =                                           \
                    wt + (size_t)(c2_) * 18432 + u * 512 + lane * 8;                  \
                unsigned short* dst = bufq + u * 512 + lane * 8;                      \
                __builtin_amdgcn_global_load_lds((g_u32_t*)src, (lds_u32_t*)dst,      \
                                                 16, 0, 0);                           \
            } else {                                                                  \
                int ua = u - 36;             /* 0..11 */                              \
                int cp = ua >= 6;                                                     \
                int q6 = ua - cp * 6;        /* 0..5 */                               \
                int z  = (((c2_) << 1) + cp) * 8 + b;                                 \
                const unsigned short* src = ft +                                      \
                    ((size_t)z * PLANE16 + y0 * 66) * 8 + q6 * 512 + lane * 8;        \
                unsigned short* dst = bufq + 18432 + cp * 3072 + q6 * 512 + lane * 8; \
                __builtin_amdgcn_global_load_lds((g_u32_t*)src, (lds_u32_t*)dst,      \
                                                 16, 0, 0);                           \
            }                                                                         \
        }                                                                             \
    }

#define DOSTEP(ao_, bo_)                                                              \
    {                                                                                 \
        short8 a0 = *(const short8*)(bufr + (ao_));                                   \
        short8 a1 = *(const short8*)(bufr + (ao_) + 256);                             \
        short8 b0 = *(const short8*)(bufr + (bo_));                                   \
        short8 b1 = *(const short8*)(bufr + (bo_) + 256);                             \
        acc00 = __builtin_amdgcn_mfma_f32_32x32x16_bf16(a0, b0, acc00, 0, 0, 0);      \
        acc01 = __builtin_amdgcn_mfma_f32_32x32x16_bf16(a0, b1, acc01, 0, 0, 0);      \
        acc10 = __builtin_amdgcn_mfma_f32_32x32x16_bf16(a1, b0, acc10, 0, 0, 0);      \
        acc11 = __builtin_amdgcn_mfma_f32_32x32x16_bf16(a1, b1, acc11, 0, 0, 0);      \
    }

#define COMPUTE(q_)                                                                   \
    {                                                                                 \
        const unsigned short* bufr = Bufs + (q_) * BUF_SHORTS;                        \
        DOSTEP(aoff0, boff0)                                                          \
        DOSTEP(aoff1, boff1)                                                          \
        DOSTEP(aoff2, boff2)                                                          \
    }

#define PHASE(q_, n_, stagec2, dostage_)                                              \
    {                                                                                 \
        asm volatile("s_waitcnt vmcnt(" #n_ ")" ::: "memory");                        \
        __builtin_amdgcn_s_barrier();                                                 \
        asm volatile("" ::: "memory");                                                \
        __builtin_amdgcn_s_setprio(1);                                                \
        COMPUTE(q_)                                                                   \
        __builtin_amdgcn_s_setprio(0);                                                \
        asm volatile("" ::: "memory");                                                \
        __builtin_amdgcn_s_barrier();                                                 \
        asm volatile("" ::: "memory");                                                \
        if (dostage_) STAGE(stagec2, q_);                                             \
    }

// Epilogue reduce helpers: conflict-free float4 layout (lane-stride 16 B).
#define DUMPA(base_, A_)                                                              \
    {   float4* s4 = (float4*)(red + (base_));                                        \
        _Pragma("unroll")                                                             \
        for (int c = 0; c < 4; ++c)                                                   \
            s4[c * 64 + lane] = make_float4(A_[4*c], A_[4*c+1], A_[4*c+2], A_[4*c+3]); }
#define ADDA(base_, A_)                                                               \
    {   const float4* s4 = (const float4*)(red + (base_));                            \
        _Pragma("unroll")                                                             \
        for (int c = 0; c < 4; ++c) {                                                 \
            float4 rv = s4[c * 64 + lane];                                            \
            A_[4*c] += rv.x; A_[4*c+1] += rv.y; A_[4*c+2] += rv.z; A_[4*c+3] += rv.w; } }
#define DUMP4(base_)                                                                  \
    { DUMPA((base_), acc00) DUMPA((base_) + 1024, acc01)                              \
      DUMPA((base_) + 2048, acc10) DUMPA((base_) + 3072, acc11) }
#define ADD4(base_)                                                                   \
    { ADDA((base_), acc00) ADDA((base_) + 1024, acc01)                                \
      ADDA((base_) + 2048, acc10) ADDA((base_) + 3072, acc11) }

__global__ __launch_bounds__(768, 3)
void convkan_gemm(const unsigned short* __restrict__ ft,
                  const unsigned short* __restrict__ wt,
                  const float* __restrict__ bias,
                  float* __restrict__ out) {
    extern __shared__ unsigned short Bufs[];     // 3 x 24576 shorts = 144 KB

    const int tid  = threadIdx.x;
    const int mb   = blockIdx.x;                 // 0..255, 128 px (2 lines) each
    const int lane = tid & 63;
    const int wave = tid >> 6;                   // 0..11
    const int sq   = wave >> 2;                  // step-third 0..2
    const int grp  = wave & 3;                   // output quadrant
    const int mh   = grp >> 1;                   // m-half = line within pair
    const int nh   = grp & 1;                    // n-half (64 ch)
    const int l32  = lane & 31;
    const int h    = lane >> 5;                  // k-half within MFMA K16

    const int b  = mb >> 5;                      // image 0..7
    const int y0 = (mb & 31) << 1;               // first of 2 lines

    // Precompute the 3 step offsets (straight-line hot loop, no branches).
    int aoff0, aoff1, aoff2, boff0, boff1, boff2;
    {
        int s, t0, cp, j, kh, kw;
        s = sq * 3 + 0; t0 = 2 * s + h; cp = t0 >= 9; j = t0 - 9 * cp;
        kh = (j * 11) >> 5; kw = j - kh * 3;
        aoff0 = 18432 + cp * 3072 + ((mh + kh) * 66 + kw) * 8 + l32 * 8;
        boff0 = t0 * 1024 + nh * 512 + l32 * 8;
        s = sq * 3 + 1; t0 = 2 * s + h; cp = t0 >= 9; j = t0 - 9 * cp;
        kh = (j * 11) >> 5; kw = j - kh * 3;
        aoff1 = 18432 + cp * 3072 + ((mh + kh) * 66 + kw) * 8 + l32 * 8;
        boff1 = t0 * 1024 + nh * 512 + l32 * 8;
        s = sq * 3 + 2; t0 = 2 * s + h; cp = t0 >= 9; j = t0 - 9 * cp;
        kh = (j * 11) >> 5; kw = j - kh * 3;
        aoff2 = 18432 + cp * 3072 + ((mh + kh) * 66 + kw) * 8 + l32 * 8;
        boff2 = t0 * 1024 + nh * 512 + l32 * 8;
    }

    f32x16 acc00, acc01, acc10, acc11;
#pragma unroll
    for (int e = 0; e < 16; ++e) { acc00[e] = 0.f; acc01[e] = 0.f; acc10[e] = 0.f; acc11[e] = 0.f; }

    // prologue: fill the 3-deep pipeline (c-pairs 0,1,2)
    STAGE(0, 0);
    STAGE(1, 1);
    STAGE(2, 2);

    // steady state: phases 0..26 stage c-pairs 3..29
    for (int it3 = 0; it3 < 9; ++it3) {
        const int it = it3 * 3;
        PHASE(0, 8, it + 3, true)
        PHASE(1, 8, it + 4, true)
        PHASE(2, 8, it + 5, true)
    }
    // phases 27..31: stage 30, 31, then drain
    PHASE(0, 8, 30, true)
    PHASE(1, 8, 31, true)
    PHASE(2, 8, 0, false)
    PHASE(0, 4, 0, false)
    PHASE(1, 0, 0, false)

    // ---- K-partial reduction across sq (one LDS round), then store ----
    __syncthreads();
    float* red = (float*)Bufs;
    const int rbase = grp * 8192;                // 2 regions x 4096 floats per grp

    if (sq == 1) DUMP4(rbase)
    if (sq == 2) DUMP4(rbase + 4096)
    __syncthreads();
    if (sq == 0) {
        ADD4(rbase)
        ADD4(rbase + 4096)

        const int ncol = nh * 64 + l32;
        const float bv0 = bias[ncol];
        const float bv1 = bias[ncol + 32];
        const int prow = mb * 128 + mh * 64;
#pragma unroll
        for (int r = 0; r < 16; ++r) {
            int mrow = (r & 3) + ((r >> 2) << 3) + 4 * h;
            float* p = out + (size_t)(prow + mrow) * 128 + ncol;
            p[0]  = acc00[r] + bv0;
            p[32] = acc01[r] + bv1;
            float* p2 = out + (size_t)(prow + 32 + mrow) * 128 + ncol;
            p2[0]  = acc10[r] + bv0;
            p2[32] = acc11[r] + bv1;
        }
    }
}

extern "C" void kernel_launch(void* const* d_in, const int* in_sizes, int n_in,
                              void* d_out, int out_size, void* d_ws, size_t ws_size,
                              hipStream_t stream) {
    (void)in_sizes; (void)n_in; (void)ws_size; (void)out_size;
    const float* x        = (const float*)d_in[0];
    const float* base_w   = (const float*)d_in[1];
    const float* spline_w = (const float*)d_in[2];
    const float* bias     = (const float*)d_in[3];
    float* out = (float*)d_out;

    unsigned short* ft = (unsigned short*)d_ws;      // 35.68 MB halo features
    unsigned short* wt = ft + FT2_SHORTS;            // 1.18 MB tiled B (i-major)

    hipLaunchKernelGGL(prep_all, dim3(512), dim3(256), 0, stream,
                       x, base_w, spline_w, ft, wt);

    const int shmem = 3 * BUF_SHORTS * 2;            // 144 KB
    (void)hipFuncSetAttribute((const void*)convkan_gemm,
                              hipFuncAttributeMaxDynamicSharedMemorySize, shmem);
    hipLaunchKernelGGL(convkan_gemm, dim3(256), dim3(768), shmem, stream,
                       ft, wt, bias, out);
}

// Round 6
// 135.743 us; speedup vs baseline: 6.9405x; 1.3047x over previous
//
#include <hip/hip_runtime.h>

typedef __attribute__((ext_vector_type(8))) short short8;
typedef __attribute__((ext_vector_type(16))) float f32x16;

// ws layout:
//   Ft2  [z=512][yy=66][xx=66][8] bf16 halo-padded features, z = c*8 + b   (35.68 MB)
//   wt2  [slab=72][e=8][n=128][8] bf16 B slabs, e = i&7 (chunk-major)      (1.18 MB)
#define FT2_SHORTS (512u * 4356u * 8u)
#define PLANE16    4356

typedef __attribute__((address_space(3))) unsigned int lds_u32_t;
typedef __attribute__((address_space(1))) const unsigned int g_u32_t;

__device__ __forceinline__ unsigned short f2bf(float x) {
    union { float f; unsigned u; } v; v.f = x;
    unsigned r = v.u + 0x7FFFu + ((v.u >> 16) & 1u);   // RNE bf16
    return (unsigned short)(r >> 16);
}

__device__ __forceinline__ void feat8(float p, unsigned short* uf) {
    float e   = __expf(-p);
    float sig = 1.f / (1.f + e);
    uf[0] = f2bf(p * sig);
    float u  = p * 1.5f + 4.5f;
    float fj = floorf(u);
    int   j0 = (int)fj;
    float t  = u - fj;
    bool  inr = (u >= 0.f) && (u < 9.f);
    float t2 = t * t, t3 = t2 * t;
    const float c16 = 1.f / 6.f;
    float r0 = t3 * c16;
    float r1 = (-3.f * t3 + 3.f * t2 + 3.f * t + 1.f) * c16;
    float r2 = (3.f * t3 - 6.f * t2 + 4.f) * c16;
    float s1 = 1.f - t;
    float r3 = s1 * s1 * s1 * c16;
#pragma unroll
    for (int g = 0; g < 6; ++g) {
        int r = j0 - g;
        float v = (r == 0) ? r0 : ((r == 1) ? r1 : ((r == 2) ? r2 : ((r == 3) ? r3 : 0.f)));
        uf[1 + g] = f2bf(inr ? v : 0.f);
    }
    uf[7] = 0;
}

// ---- Fused prep: per block (512): 144 B-chunks + 1 halo plane + 1 feature line ----
__global__ __launch_bounds__(256)
void prep_all(const float* __restrict__ x,
              const float* __restrict__ bw, const float* __restrict__ sw,
              unsigned short* __restrict__ ft, unsigned short* __restrict__ wt) {
    const int blk = blockIdx.x;          // 0..511
    const int tid = threadIdx.x;

    // (1) B prep into slab-chunk-major layout: wt[slab][i&7][n][8]
    if (tid < 144) {
        int idx = blk * 144 + tid;
        int o = idx / 576;
        int i = idx - o * 576;
        int slab = i >> 3, e = i & 7;
        union { unsigned short u[8]; uint4 v; } pk;
        pk.u[0] = f2bf(bw[o * 576 + i]);
        const float* s = sw + (size_t)(o * 576 + i) * 6;
#pragma unroll
        for (int f = 0; f < 6; ++f) pk.u[1 + f] = f2bf(s[f]);
        pk.u[7] = 0;
        *(uint4*)(wt + ((size_t)slab * 8192 + e * 1024 + o * 8)) = pk.v;
    }

    // (2) halo plane z = blk: feat8(0) into the 260 border cells
    {
        short8 pad = { 0, 0, (short)0x3CAB, (short)0x3EF5,
                       (short)0x3EF5, (short)0x3CAB, 0, 0 };
        for (int t = tid; t < 260; t += 256) {
            int yy, xx;
            if (t < 66)       { yy = 0;       xx = t; }
            else if (t < 132) { yy = 65;      xx = t - 66; }
            else if (t < 196) { yy = t - 131; xx = 0; }
            else              { yy = t - 195; xx = 65; }
            ((short8*)ft)[blk * PLANE16 + yy * 66 + xx] = pad;
        }
    }

    // (3) features for line = blk (b = blk>>6, y = blk&63)
    __shared__ float Xl[64 * 65];
    const int b = blk >> 6, y = blk & 63;
    const float* xl = x + (size_t)blk * 4096;
    for (int f4 = tid; f4 < 1024; f4 += 256) {
        float4 v = ((const float4*)xl)[f4];
        int xx = f4 >> 4, c4 = (f4 & 15) << 2;
        float* d = &Xl[xx * 65 + c4];
        d[0] = v.x; d[1] = v.y; d[2] = v.z; d[3] = v.w;
    }
    __syncthreads();
    const int xx = tid & 63;
    const int cw = tid >> 6;
#pragma unroll 4
    for (int p = 0; p < 16; ++p) {
        int c = cw + (p << 2);
        float pv = Xl[xx * 65 + c];
        union { unsigned short u[8]; uint4 v; } pk;
        feat8(pv, pk.u);
        size_t o16 = (size_t)(c * 8 + b) * PLANE16 + (y + 1) * 66 + (xx + 1);
        *(uint4*)(ft + (o16 << 3)) = pk.v;
    }
}

// ---- Main GEMM: tile 64m(1 line) x 128n, FULL K, grid 512, block 512 (8 waves) ----
// TWO blocks per CU (72 KB LDS each) = two INDEPENDENT barrier domains: one
// block's MFMA fills the other's vmcnt/barrier stalls (R3's ~45% stall budget).
// Waves (kq 0..3, nh): kq splits the slab's 8 e-chunks (iloc = kq*2+h); wave
// tile 64m x 64n, 4 accs, 4 MFMA + 4 ds_read_b128 per phase (R3's proven shape).
// Staging per slab: B 16 KB (16 loads) + A 8 rows x 1 KB (8 loads) = 24 = 3/wave.
// Triple-buffered 3 x 24 KB = 72 KB; steady vmcnt(6) (2 phases in flight).
// XCD swizzle: mb = (blk&7)*64 + blk>>3 -> each XCD owns one image b; its ft
// working set (~4.5 MB) fits its L2; halo rows shared within the XCD.
// Epilogue: 3-round LDS reduction across kq, then coalesced stores.
#define BUF_SHORTS 12288

#define STAGE(sl, q_)                                                                 \
    {                                                                                 \
        unsigned short* bufq = Bufs + (q_) * BUF_SHORTS;                              \
        const unsigned short* bsrc = wt + (size_t)(sl) * 8192;                        \
        _Pragma("unroll")                                                             \
        for (int t = 0; t < 3; ++t) {                                                 \
            int u = wave * 3 + t;            /* 0..23: u<16 = B, u>=16 = A */         \
            if (u < 16) {                                                             \
                int boff = u * 512 + lane * 8;                                        \
                __builtin_amdgcn_global_load_lds((g_u32_t*)(bsrc + boff),             \
                                                 (lds_u32_t*)(bufq + boff), 16, 0, 0);\
            } else {                                                                  \
                int idx = u - 16;            /* chunk 0..7 */                         \
                int ia  = (sl) * 8 + idx;                                             \
                int c_  = (ia * 7282) >> 16;                                          \
                int i9_ = ia - c_ * 9;                                                \
                int kh_ = (i9_ * 11) >> 5;                                            \
                int kw_ = i9_ - kh_ * 3;                                              \
                const unsigned short* asrc = ft +                                     \
                    (((size_t)(c_ * 8 + b) * PLANE16 + (y + kh_) * 66 + kw_) << 3)    \
                    + lane * 8;                                                       \
                unsigned short* adst = bufq + 8192 + idx * 512 + lane * 8;            \
                __builtin_amdgcn_global_load_lds((g_u32_t*)asrc, (lds_u32_t*)adst,    \
                                                 16, 0, 0);                           \
            }                                                                         \
        }                                                                             \
    }

#define COMPUTE(q_)                                                                   \
    {                                                                                 \
        const unsigned short* bufr = Bufs + (q_) * BUF_SHORTS;                        \
        const unsigned short* Ab = bufr + 8192 + iloc * 512;                          \
        const unsigned short* Bb = bufr + iloc * 1024 + nh * 512;                     \
        short8 a0 = *(const short8*)(Ab + l32 * 8);                                   \
        short8 a1 = *(const short8*)(Ab + (32 + l32) * 8);                            \
        short8 b0 = *(const short8*)(Bb + l32 * 8);                                   \
        short8 b1 = *(const short8*)(Bb + 256 + l32 * 8);                             \
        acc00 = __builtin_amdgcn_mfma_f32_32x32x16_bf16(a0, b0, acc00, 0, 0, 0);      \
        acc01 = __builtin_amdgcn_mfma_f32_32x32x16_bf16(a0, b1, acc01, 0, 0, 0);      \
        acc10 = __builtin_amdgcn_mfma_f32_32x32x16_bf16(a1, b0, acc10, 0, 0, 0);      \
        acc11 = __builtin_amdgcn_mfma_f32_32x32x16_bf16(a1, b1, acc11, 0, 0, 0);      \
    }

#define PHASE(q_, n_, stagesl, dostage_)                                              \
    {                                                                                 \
        asm volatile("s_waitcnt vmcnt(" #n_ ")" ::: "memory");                        \
        __builtin_amdgcn_s_barrier();                                                 \
        asm volatile("" ::: "memory");                                                \
        __builtin_amdgcn_s_setprio(1);                                                \
        COMPUTE(q_)                                                                   \
        __builtin_amdgcn_s_setprio(0);                                                \
        asm volatile("" ::: "memory");                                                \
        __builtin_amdgcn_s_barrier();                                                 \
        asm volatile("" ::: "memory");                                                \
        if (dostage_) STAGE(stagesl, q_);                                             \
    }

// Epilogue reduce helpers: conflict-free float4 layout (lane-stride 16 B).
#define DUMPA(base_, A_)                                                              \
    {   float4* s4 = (float4*)(red + (base_));                                        \
        _Pragma("unroll")                                                             \
        for (int c = 0; c < 4; ++c)                                                   \
            s4[c * 64 + lane] = make_float4(A_[4*c], A_[4*c+1], A_[4*c+2], A_[4*c+3]); }
#define ADDA(base_, A_)                                                               \
    {   const float4* s4 = (const float4*)(red + (base_));                            \
        _Pragma("unroll")                                                             \
        for (int c = 0; c < 4; ++c) {                                                 \
            float4 rv = s4[c * 64 + lane];                                            \
            A_[4*c] += rv.x; A_[4*c+1] += rv.y; A_[4*c+2] += rv.z; A_[4*c+3] += rv.w; } }

__global__ __launch_bounds__(512, 4)
void convkan_gemm(const unsigned short* __restrict__ ft,
                  const unsigned short* __restrict__ wt,
                  const float* __restrict__ bias,
                  float* __restrict__ out) {
    extern __shared__ unsigned short Bufs[];     // 3 x 12288 shorts = 72 KB

    const int tid  = threadIdx.x;
    const int blk  = blockIdx.x;                 // 0..511
    const int mb   = ((blk & 7) << 6) | (blk >> 3);  // XCD swizzle: XCD owns image
    const int lane = tid & 63;
    const int wave = tid >> 6;                   // 0..7
    const int kq   = wave >> 1;                  // K-quarter 0..3
    const int nh   = wave & 1;                   // n-half (64 ch)
    const int l32  = lane & 31;
    const int h    = lane >> 5;                  // k-half within MFMA K16
    const int iloc = (kq << 1) + h;              // e-chunk this half-wave consumes

    const int b = mb >> 6;                       // image 0..7
    const int y = mb & 63;                       // line 0..63

    f32x16 acc00, acc01, acc10, acc11;
#pragma unroll
    for (int e = 0; e < 16; ++e) { acc00[e] = 0.f; acc01[e] = 0.f; acc10[e] = 0.f; acc11[e] = 0.f; }

    // prologue: fill the 3-deep pipeline
    STAGE(0, 0);
    STAGE(1, 1);
    STAGE(2, 2);

    // steady state: phases 0..68 stage slabs 3..71
    for (int it3 = 0; it3 < 23; ++it3) {
        const int it = it3 * 3;
        PHASE(0, 6, it + 3, true)
        PHASE(1, 6, it + 4, true)
        PHASE(2, 6, it + 5, true)
    }
    // tail: phases 69, 70, 71 — drain pipeline
    PHASE(0, 6, 0, false)
    PHASE(1, 3, 0, false)
    PHASE(2, 0, 0, false)

    // ---- K-partial reduction across kq (3 rounds via LDS), then store ----
    __syncthreads();
    float* red = (float*)Bufs;

    if (kq >= 2) { DUMPA(((nh << 1) + (kq - 2)) * 2048,        acc00);
                   DUMPA(((nh << 1) + (kq - 2)) * 2048 + 1024, acc01); }
    __syncthreads();
    if (kq < 2)  { ADDA(((nh << 1) + kq) * 2048,        acc00);
                   ADDA(((nh << 1) + kq) * 2048 + 1024, acc01); }
    __syncthreads();
    if (kq >= 2) { DUMPA(((nh << 1) + (kq - 2)) * 2048,        acc10);
                   DUMPA(((nh << 1) + (kq - 2)) * 2048 + 1024, acc11); }
    __syncthreads();
    if (kq < 2)  { ADDA(((nh << 1) + kq) * 2048,        acc10);
                   ADDA(((nh << 1) + kq) * 2048 + 1024, acc11); }
    __syncthreads();
    if (kq == 1) { DUMPA(nh * 4096,        acc00); DUMPA(nh * 4096 + 1024, acc01);
                   DUMPA(nh * 4096 + 2048, acc10); DUMPA(nh * 4096 + 3072, acc11); }
    __syncthreads();
    if (kq == 0) {
        ADDA(nh * 4096,        acc00); ADDA(nh * 4096 + 1024, acc01);
        ADDA(nh * 4096 + 2048, acc10); ADDA(nh * 4096 + 3072, acc11);

        const int ncol = nh * 64 + l32;
        const float bv0 = bias[ncol];
        const float bv1 = bias[ncol + 32];
        const int prow = mb * 64;                // output pixel-row base
#pragma unroll
        for (int r = 0; r < 16; ++r) {
            int mrow = (r & 3) + ((r >> 2) << 3) + 4 * h;
            float* p = out + (size_t)(prow + mrow) * 128 + ncol;
            p[0]  = acc00[r] + bv0;
            p[32] = acc01[r] + bv1;
            float* p2 = out + (size_t)(prow + 32 + mrow) * 128 + ncol;
            p2[0]  = acc10[r] + bv0;
            p2[32] = acc11[r] + bv1;
        }
    }
}

extern "C" void kernel_launch(void* const* d_in, const int* in_sizes, int n_in,
                              void* d_out, int out_size, void* d_ws, size_t ws_size,
                              hipStream_t stream) {
    (void)in_sizes; (void)n_in; (void)ws_size; (void)out_size;
    const float* x        = (const float*)d_in[0];
    const float* base_w   = (const float*)d_in[1];
    const float* spline_w = (const float*)d_in[2];
    const float* bias     = (const float*)d_in[3];
    float* out = (float*)d_out;

    unsigned short* ft = (unsigned short*)d_ws;      // 35.68 MB halo features
    unsigned short* wt = ft + FT2_SHORTS;            // 1.18 MB tiled B (slab-major)

    hipLaunchKernelGGL(prep_all, dim3(512), dim3(256), 0, stream,
                       x, base_w, spline_w, ft, wt);

    const int shmem = 3 * BUF_SHORTS * 2;            // 72 KB -> 2 blocks/CU
    (void)hipFuncSetAttribute((const void*)convkan_gemm,
                              hipFuncAttributeMaxDynamicSharedMemorySize, shmem);
    hipLaunchKernelGGL(convkan_gemm, dim3(512), dim3(512), shmem, stream,
                       ft, wt, bias, out);
}